// Round 8
// baseline (415.312 us; speedup 1.0000x reference)
//
#include <hip/hip_runtime.h>
#include <stdint.h>

#define NN 16384
#define DD 128
#define KT 64        // k-tile rows
#define QB 128       // q rows per block (4 waves x 32)

typedef float f32x16 __attribute__((ext_vector_type(16)));
typedef int i32x8 __attribute__((ext_vector_type(8)));

__device__ __forceinline__ i32x8 mk8(uint4 a, uint4 b) {
  i32x8 r;
  r[0] = a.x; r[1] = a.y; r[2] = a.z; r[3] = a.w;
  r[4] = b.x; r[5] = b.y; r[6] = b.z; r[7] = b.w;
  return r;
}

#define MFMA64(A, B, C) \
  __builtin_amdgcn_mfma_scale_f32_32x32x64_f8f6f4((A), (B), (C), 0, 0, 0, 0x7F7F7F7F, 0, 0x7F7F7F7F)

// K1: row L2-norms -> nx fp8 (e4m3), scaled by sqrt(log2(e)) so QK^T dots
// come out pre-multiplied by log2(e) -> softmax is a bare v_exp_f32 (2^x).
__global__ void k_norm(const float* __restrict__ x, uint8_t* __restrict__ nx) {
  const int wave = threadIdx.x >> 6, lane = threadIdx.x & 63;
  const int row = blockIdx.x * 4 + wave;
  const float2 v = *reinterpret_cast<const float2*>(x + (size_t)row * DD + 2 * lane);
  float ss = v.x * v.x + v.y * v.y;
#pragma unroll
  for (int m = 1; m < 64; m <<= 1) ss += __shfl_xor(ss, m);
  const float rn = 1.2011224087f / fmaxf(sqrtf(ss), 1e-12f);  // sqrt(log2 e)/|x|
  const int w = __builtin_amdgcn_cvt_pk_fp8_f32(v.x * rn, v.y * rn, 0, false);
  *reinterpret_cast<uint16_t*>(nx + (size_t)row * DD + 2 * lane) = (uint16_t)w;
}

// K1b: transpose x (fp32 [N][D]) -> xT (fp8 [D][N]) via LDS tile.
__global__ void k_transpose(const float* __restrict__ x, uint8_t* __restrict__ xT) {
  __shared__ uint16_t tile[64 * 66];  // 64 n-rows x 128 d fp8, row stride 132B
  const int n0 = blockIdx.x * 64;
  const int t = threadIdx.x;
#pragma unroll
  for (int e = 0; e < 16; ++e) {
    const int idx = e * 256 + t;
    const int r = idx >> 6, c2 = idx & 63;
    const float2 v = *reinterpret_cast<const float2*>(x + (size_t)(n0 + r) * DD + 2 * c2);
    const int w = __builtin_amdgcn_cvt_pk_fp8_f32(v.x, v.y, 0, false);
    tile[r * 66 + c2] = (uint16_t)w;
  }
  __syncthreads();
  const uint8_t* t8 = reinterpret_cast<const uint8_t*>(tile);
#pragma unroll
  for (int e = 0; e < 8; ++e) {
    const int idx = e * 256 + t;
    const int d = idx >> 4, n4 = (idx & 15) << 2;
    uint32_t w = (uint32_t)t8[(n4 + 0) * 132 + d];
    w |= (uint32_t)t8[(n4 + 1) * 132 + d] << 8;
    w |= (uint32_t)t8[(n4 + 2) * 132 + d] << 16;
    w |= (uint32_t)t8[(n4 + 3) * 132 + d] << 24;
    *reinterpret_cast<uint32_t*>(xT + (size_t)d * NN + n0 + n4) = w;
  }
}

// K2: flash attention, barrier-free / LDS-free, with DISTANCE-1 REGISTER
// PREFETCH: while computing tile t from reg-set A, tile t+1's K/V fragments
// load into reg-set B (two-tile unrolled loop, all-static indexing).
// MX-scaled fp8 32x32x64 MFMA; swapped QK^T; in-register softmax; P packed
// to fp8 A-frags via cvt_pk_fp8 + 4x permlane32_swap.
template <int NSPLIT>
__global__ __launch_bounds__(256, 2) void k_attn(
    const uint8_t* __restrict__ nx, const uint8_t* __restrict__ xT,
    float* __restrict__ Op, float* __restrict__ Lp) {
  const int tid = threadIdx.x;
  const int wave = tid >> 6;
  const int lane = tid & 63;
  const int rl = lane & 31;
  const int hi = lane >> 5;

  // XCD-grouped: split s lives on XCD s-group -> its K/V slice L2-resident.
  const int id = blockIdx.x;
  constexpr int gs = 8 / NSPLIT;
  const int split = (id & 7) / gs;
  const int qblock = (id >> 3) * gs + (id & (gs - 1));

  constexpr int nt = 256 / NSPLIT;   // even for NSPLIT in {2,4,8}
  const int t0s = split * nt;
  const int qw = qblock * QB + wave * 32;

  // Q B-frags (fp8): col q = l&31, d = c*64 + 32*hi + 0..31
  const uint8_t* qrow = nx + (size_t)(qw + rl) * DD + 32 * hi;
  i32x8 q8[2];
#pragma unroll
  for (int c = 0; c < 2; ++c)
    q8[c] = mk8(*reinterpret_cast<const uint4*>(qrow + c * 64),
                *reinterpret_cast<const uint4*>(qrow + c * 64 + 16));

  f32x16 o[4];
#pragma unroll
  for (int dt = 0; dt < 4; ++dt)
#pragma unroll
    for (int r = 0; r < 16; ++r) o[dt][r] = 0.f;
  float lsum = 0.f;

  const uint8_t* kbase = nx + (size_t)rl * DD + 32 * hi;   // + k*DD
  const uint8_t* vbase = xT + (size_t)rl * NN + 32 * hi;   // + dt*32*NN + k0

#define LD16(p) (*reinterpret_cast<const uint4*>(p))
#define LOADKV(T, kr, vr)                                               \
  do {                                                                  \
    const uint8_t* kp_ = kbase + (size_t)(t0s + (T)) * (KT * DD);       \
    kr[0] = LD16(kp_);      kr[1] = LD16(kp_ + 16);                     \
    kr[2] = LD16(kp_ + 64); kr[3] = LD16(kp_ + 80);                     \
    kp_ += 32 * DD;                                                     \
    kr[4] = LD16(kp_);      kr[5] = LD16(kp_ + 16);                     \
    kr[6] = LD16(kp_ + 64); kr[7] = LD16(kp_ + 80);                     \
    const uint8_t* vp_ = vbase + (size_t)(t0s + (T)) * KT;              \
    vr[0] = LD16(vp_);      vr[1] = LD16(vp_ + 16); vp_ += 32 * NN;     \
    vr[2] = LD16(vp_);      vr[3] = LD16(vp_ + 16); vp_ += 32 * NN;     \
    vr[4] = LD16(vp_);      vr[5] = LD16(vp_ + 16); vp_ += 32 * NN;     \
    vr[6] = LD16(vp_);      vr[7] = LD16(vp_ + 16);                     \
  } while (0)

  auto compute = [&](const uint4* kr, const uint4* vr) {
    // ---- QK^T (swapped): S^T[k][q] per 32-row k-subtile ----
    uint32_t W0[4], W1[4];
#pragma unroll
    for (int kt = 0; kt < 2; ++kt) {
      const i32x8 ka0 = mk8(kr[4 * kt + 0], kr[4 * kt + 1]);
      const i32x8 ka1 = mk8(kr[4 * kt + 2], kr[4 * kt + 3]);
      f32x16 s = {};
      s = MFMA64(ka0, q8[0], s);
      s = MFMA64(ka1, q8[1], s);
      // softmax: p = 2^s (pre-scaled by log2 e, |s|<=1.45 -> no max), then
      // pack word W[kt][g] = k {8g+4hi+0..3} (+32kt) from s[4g+0..3]
      float e[16];
#pragma unroll
      for (int r = 0; r < 16; ++r) {
        float p;
        asm("v_exp_f32 %0, %1" : "=v"(p) : "v"(s[r]));
        e[r] = p;
        lsum += p;
      }
      uint32_t* W = kt ? W1 : W0;
#pragma unroll
      for (int g = 0; g < 4; ++g) {
        uint32_t w = (uint32_t)__builtin_amdgcn_cvt_pk_fp8_f32(e[4 * g + 0], e[4 * g + 1], 0, false);
        w = (uint32_t)__builtin_amdgcn_cvt_pk_fp8_f32(e[4 * g + 2], e[4 * g + 3], (int)w, true);
        W[g] = w;
      }
    }
    // redistribute: after swap, frag bytes are linear k = 32*hi + b
#pragma unroll
    for (int g = 0; g < 4; ++g)
      asm("v_permlane32_swap_b32 %0, %1" : "+v"(W0[g]), "+v"(W1[g]));
    i32x8 pa;
    pa[0] = (int)W0[0]; pa[1] = (int)W1[0]; pa[2] = (int)W0[1]; pa[3] = (int)W1[1];
    pa[4] = (int)W0[2]; pa[5] = (int)W1[2]; pa[6] = (int)W0[3]; pa[7] = (int)W1[3];

    // ---- PV: O[q][d] += P * V, one K=64 chunk, 4 independent d-tiles ----
    o[0] = MFMA64(pa, mk8(vr[0], vr[1]), o[0]);
    o[1] = MFMA64(pa, mk8(vr[2], vr[3]), o[1]);
    o[2] = MFMA64(pa, mk8(vr[4], vr[5]), o[2]);
    o[3] = MFMA64(pa, mk8(vr[6], vr[7]), o[3]);
  };

  uint4 krA[8], vrA[8], krB[8], vrB[8];
  LOADKV(0, krA, vrA);
  LOADKV(1, krB, vrB);
  for (int t = 0; t + 2 < nt; t += 2) {
    compute(krA, vrA);           // tile t   (B-loads in flight)
    LOADKV(t + 2, krA, vrA);     // prefetch tile t+2 into A
    compute(krB, vrB);           // tile t+1 (A-loads in flight)
    LOADKV(t + 3, krB, vrB);     // prefetch tile t+3 into B (t+3 <= nt-1)
  }
  compute(krA, vrA);             // tile nt-2
  compute(krB, vrB);             // tile nt-1

  // L[q]: lanes l and l+32 hold complementary k-subsets of the same q
  const float lt = lsum + __shfl_xor(lsum, 32);
  if (hi == 0) Lp[(size_t)split * NN + qw + rl] = lt;

  float* Ob = Op + (size_t)split * NN * DD;
#pragma unroll
  for (int dt = 0; dt < 4; ++dt)
#pragma unroll
    for (int r = 0; r < 16; ++r) {
      const int q = (r & 3) + 8 * (r >> 2) + 4 * hi;
      Ob[(size_t)(qw + q) * DD + dt * 32 + rl] = o[dt][r];
    }
}

// K3: combine splits, y = 1.5x - 0.5*(O/L), LayerNorm over D, write fp32 out.
__global__ void k_final(const float* __restrict__ x, const float* __restrict__ gamma,
                        const float* __restrict__ beta, const float* __restrict__ Op,
                        const float* __restrict__ Lp, float* __restrict__ out, int nsplit) {
  const int wave = threadIdx.x >> 6, lane = threadIdx.x & 63;
  const int row = blockIdx.x * 4 + wave;
  float o0 = 0.f, o1 = 0.f, lt = 0.f;
  for (int s = 0; s < nsplit; ++s) {
    const float2 v = *reinterpret_cast<const float2*>(
        Op + (size_t)s * NN * DD + (size_t)row * DD + 2 * lane);
    o0 += v.x;
    o1 += v.y;
    lt += Lp[(size_t)s * NN + row];
  }
  const float inv = 1.0f / lt;
  const float2 xv = *reinterpret_cast<const float2*>(x + (size_t)row * DD + 2 * lane);
  float y0 = 1.5f * xv.x - 0.5f * o0 * inv;
  float y1 = 1.5f * xv.y - 0.5f * o1 * inv;
  float sum = y0 + y1;
#pragma unroll
  for (int m = 1; m < 64; m <<= 1) sum += __shfl_xor(sum, m);
  const float mu = sum * (1.0f / 128.0f);
  const float d0 = y0 - mu, d1 = y1 - mu;
  float vs = d0 * d0 + d1 * d1;
#pragma unroll
  for (int m = 1; m < 64; m <<= 1) vs += __shfl_xor(vs, m);
  const float rs = rsqrtf(vs * (1.0f / 128.0f) + 1e-5f);
  const float2 g = *reinterpret_cast<const float2*>(gamma + 2 * lane);
  const float2 b = *reinterpret_cast<const float2*>(beta + 2 * lane);
  float2 ov;
  ov.x = d0 * rs * g.x + b.x;
  ov.y = d1 * rs * g.y + b.y;
  *reinterpret_cast<float2*>(out + (size_t)row * DD + 2 * lane) = ov;
}

extern "C" void kernel_launch(void* const* d_in, const int* in_sizes, int n_in,
                              void* d_out, int out_size, void* d_ws, size_t ws_size,
                              hipStream_t stream) {
  const float* x = (const float*)d_in[0];
  const float* gamma = (const float*)d_in[1];
  const float* beta = (const float*)d_in[2];
  float* out = (float*)d_out;
  char* ws = (char*)d_ws;

  uint8_t* nx = (uint8_t*)ws;                           // 2 MiB fp8 [N][D], scaled
  uint8_t* xT = (uint8_t*)(ws + (size_t)NN * DD);       // 2 MiB fp8 [D][N]
  const size_t base = (size_t)2 * NN * DD;
  const size_t per = (size_t)NN * DD * 4 + (size_t)NN * 4;  // per-split O + L

  int nsplit = 2;
  if (ws_size >= base + 8 * per) nsplit = 8;
  else if (ws_size >= base + 4 * per) nsplit = 4;

  float* Op = (float*)(ws + base);
  float* Lp = (float*)(ws + base + (size_t)nsplit * NN * DD * 4);

  k_norm<<<NN / 4, 256, 0, stream>>>(x, nx);
  k_transpose<<<NN / 64, 256, 0, stream>>>(x, xT);
  if (nsplit == 8)
    k_attn<8><<<dim3(128 * 8), 256, 0, stream>>>(nx, xT, Op, Lp);
  else if (nsplit == 4)
    k_attn<4><<<dim3(128 * 4), 256, 0, stream>>>(nx, xT, Op, Lp);
  else
    k_attn<2><<<dim3(128 * 2), 256, 0, stream>>>(nx, xT, Op, Lp);
  k_final<<<NN / 4, 256, 0, stream>>>(x, gamma, beta, Op, Lp, out, nsplit);
}

// Round 9
// 157.687 us; speedup vs baseline: 2.6338x; 2.6338x over previous
//
#include <hip/hip_runtime.h>
#include <stdint.h>

#define NN 16384
#define DD 128
#define QB 128       // q rows per block (4 waves x 32)
#define KSTR 144     // K LDS row stride (128 data + 16 pad)
#define VSTR 72      // V^T LDS row stride (64 data + 8 pad)
#define TBYTES 9216  // one tile buffer: 64*144 == 128*72

typedef float f32x16 __attribute__((ext_vector_type(16)));
typedef int i32x8 __attribute__((ext_vector_type(8)));

using gv = __attribute__((address_space(1))) const void;
using lv = __attribute__((address_space(3))) void;

__device__ __forceinline__ i32x8 mk8(uint4 a, uint4 b) {
  i32x8 r;
  r[0] = a.x; r[1] = a.y; r[2] = a.z; r[3] = a.w;
  r[4] = b.x; r[5] = b.y; r[6] = b.z; r[7] = b.w;
  return r;
}

#define MFMA64(A, B, C) \
  __builtin_amdgcn_mfma_scale_f32_32x32x64_f8f6f4((A), (B), (C), 0, 0, 0, 0x7F7F7F7F, 0, 0x7F7F7F7F)
#define LD16(p) (*reinterpret_cast<const uint4*>(p))

// K1: row L2-norms -> nx fp8 (e4m3), scaled by sqrt(log2(e)) so QK^T dots
// come out pre-multiplied by log2(e) -> softmax is a bare v_exp_f32 (2^x).
__global__ void k_norm(const float* __restrict__ x, uint8_t* __restrict__ nx) {
  const int wave = threadIdx.x >> 6, lane = threadIdx.x & 63;
  const int row = blockIdx.x * 4 + wave;
  const float2 v = *reinterpret_cast<const float2*>(x + (size_t)row * DD + 2 * lane);
  float ss = v.x * v.x + v.y * v.y;
#pragma unroll
  for (int m = 1; m < 64; m <<= 1) ss += __shfl_xor(ss, m);
  const float rn = 1.2011224087f / fmaxf(sqrtf(ss), 1e-12f);  // sqrt(log2 e)/|x|
  const int w = __builtin_amdgcn_cvt_pk_fp8_f32(v.x * rn, v.y * rn, 0, false);
  *reinterpret_cast<uint16_t*>(nx + (size_t)row * DD + 2 * lane) = (uint16_t)w;
}

// K1b: transpose x (fp32 [N][D]) -> xT (fp8 [D][N]) via LDS tile.
__global__ void k_transpose(const float* __restrict__ x, uint8_t* __restrict__ xT) {
  __shared__ uint16_t tile[64 * 66];
  const int n0 = blockIdx.x * 64;
  const int t = threadIdx.x;
#pragma unroll
  for (int e = 0; e < 16; ++e) {
    const int idx = e * 256 + t;
    const int r = idx >> 6, c2 = idx & 63;
    const float2 v = *reinterpret_cast<const float2*>(x + (size_t)(n0 + r) * DD + 2 * c2);
    const int w = __builtin_amdgcn_cvt_pk_fp8_f32(v.x, v.y, 0, false);
    tile[r * 66 + c2] = (uint16_t)w;
  }
  __syncthreads();
  const uint8_t* t8 = reinterpret_cast<const uint8_t*>(tile);
#pragma unroll
  for (int e = 0; e < 8; ++e) {
    const int idx = e * 256 + t;
    const int d = idx >> 4, n4 = (idx & 15) << 2;
    uint32_t w = (uint32_t)t8[(n4 + 0) * 132 + d];
    w |= (uint32_t)t8[(n4 + 1) * 132 + d] << 8;
    w |= (uint32_t)t8[(n4 + 2) * 132 + d] << 16;
    w |= (uint32_t)t8[(n4 + 3) * 132 + d] << 24;
    *reinterpret_cast<uint32_t*>(xT + (size_t)d * NN + n0 + n4) = w;
  }
}

// ---- per-tile compute macros (all static names, no runtime-indexed arrays) --
#define QKT(kb_, s0_, s1_)                                                \
  {                                                                       \
    const uint8_t* kbb_ = (kb_) + rl * KSTR + 32 * hi;                    \
    i32x8 a_;                                                             \
    a_ = mk8(LD16(kbb_), LD16(kbb_ + 16));                                \
    s0_ = MFMA64(a_, q80, s0_);                                           \
    a_ = mk8(LD16(kbb_ + 64), LD16(kbb_ + 80));                           \
    s0_ = MFMA64(a_, q81, s0_);                                           \
    const uint8_t* kb1_ = kbb_ + 32 * KSTR;                               \
    a_ = mk8(LD16(kb1_), LD16(kb1_ + 16));                                \
    s1_ = MFMA64(a_, q80, s1_);                                           \
    a_ = mk8(LD16(kb1_ + 64), LD16(kb1_ + 80));                           \
    s1_ = MFMA64(a_, q81, s1_);                                           \
  }

#define SMPACK(sv_, W_)                                                   \
  {                                                                       \
    _Pragma("unroll") for (int g = 0; g < 4; ++g) {                       \
      float e0_, e1_, e2_, e3_;                                           \
      asm("v_exp_f32 %0, %1" : "=v"(e0_) : "v"(sv_[4 * g + 0]));          \
      asm("v_exp_f32 %0, %1" : "=v"(e1_) : "v"(sv_[4 * g + 1]));          \
      asm("v_exp_f32 %0, %1" : "=v"(e2_) : "v"(sv_[4 * g + 2]));          \
      asm("v_exp_f32 %0, %1" : "=v"(e3_) : "v"(sv_[4 * g + 3]));          \
      lsum += (e0_ + e1_) + (e2_ + e3_);                                  \
      uint32_t w_ = (uint32_t)__builtin_amdgcn_cvt_pk_fp8_f32(e0_, e1_, 0, false); \
      w_ = (uint32_t)__builtin_amdgcn_cvt_pk_fp8_f32(e2_, e3_, (int)w_, true);     \
      W_[g] = w_;                                                         \
    }                                                                     \
  }

#define MKPA(pa_, W0_, W1_)                                               \
  _Pragma("unroll") for (int g = 0; g < 4; ++g)                           \
      asm("v_permlane32_swap_b32 %0, %1" : "+v"(W0_[g]), "+v"(W1_[g]));   \
  i32x8 pa_;                                                              \
  pa_[0] = (int)W0_[0]; pa_[1] = (int)W1_[0];                             \
  pa_[2] = (int)W0_[1]; pa_[3] = (int)W1_[1];                             \
  pa_[4] = (int)W0_[2]; pa_[5] = (int)W1_[2];                             \
  pa_[6] = (int)W0_[3]; pa_[7] = (int)W1_[3];

#define PVT(vb_, pa_)                                                     \
  {                                                                       \
    const uint8_t* vp_ = (vb_) + rl * VSTR + 32 * hi;                     \
    o[0] = MFMA64(pa_, mk8(LD16(vp_), LD16(vp_ + 16)), o[0]);             \
    o[1] = MFMA64(pa_, mk8(LD16(vp_ + 32 * VSTR), LD16(vp_ + 32 * VSTR + 16)), o[1]); \
    o[2] = MFMA64(pa_, mk8(LD16(vp_ + 64 * VSTR), LD16(vp_ + 64 * VSTR + 16)), o[2]); \
    o[3] = MFMA64(pa_, mk8(LD16(vp_ + 96 * VSTR), LD16(vp_ + 96 * VSTR + 16)), o[3]); \
  }

// K2: flash attention. 4 waves x 32 q-rows; MX-scaled fp8 32x32x64 MFMA;
// TWO independent 64-row k-tiles (A,B) per barrier phase so SM_A's VALU
// overlaps QK_B/PV_A's MFMA within one wave; per-block k-start rotation
// de-phases co-resident blocks (k-order is sum-invariant: no max tracking).
// K/V staged via global_load_lds into padded LDS (144/72, conflict-free).
template <int NSPLIT>
__global__ __launch_bounds__(256, 2) void k_attn(
    const uint8_t* __restrict__ nx, const uint8_t* __restrict__ xT,
    float* __restrict__ Op, float* __restrict__ Lp) {
  __shared__ alignas(16) uint8_t LDSU[2][4][TBYTES];  // [buf][KA,KB,VA,VB]

  const int tid = threadIdx.x;
  const int wave = tid >> 6;
  const int lane = tid & 63;
  const int rl = lane & 31;
  const int hi = lane >> 5;

  const int id = blockIdx.x;
  constexpr int gs = 8 / NSPLIT;
  const int split = (id & 7) / gs;
  const int qblock = (id >> 3) * gs + (id & (gs - 1));
  constexpr int nph = 128 / NSPLIT;            // phases (128 k-rows each)
  const int r0s = split * (NN / NSPLIT);       // first k-row of split
  const int pst = ((id >> 3) + ((id >> 8) << 4)) & (nph - 1);
  const int qw = qblock * QB + wave * 32;

  // staging: each wave fills LDSU[buf][wave] (9 x 1024B units)
  const bool isK = wave < 2;
  uint32_t soff[9];
#pragma unroll
  for (int i = 0; i < 9; ++i) {
    const int t16 = i * 64 + lane;
    if (isK) {
      soff[i] = (uint32_t)((t16 / 9) * DD + (t16 % 9) * 16);
    } else {
      const int d = (2 * t16) / 9;
      const int c0 = t16 * 16 - d * VSTR;
      soff[i] = (uint32_t)(d * NN + c0 + (c0 >= 64 ? (NN - VSTR) : 0));
    }
  }
  const int woff = (wave & 1) * 64;  // tile-B offset (rows for K, cols for V)

  auto stage = [&](int phm, int buf) {
    const size_t r0 = (size_t)r0s + (size_t)phm * 128 + woff;
    const uint8_t* basep = isK ? (nx + r0 * DD) : (xT + r0);
    uint8_t* ldsb = &LDSU[buf][wave][0];
#pragma unroll
    for (int i = 0; i < 9; ++i)
      __builtin_amdgcn_global_load_lds((gv*)(basep + soff[i]),
          (lv*)(ldsb + i * 1024), 16, 0, 0);
  };

  // Q B-frags (fp8): col q = l&31, d = c*64 + 32*hi + 0..31
  const uint8_t* qrow = nx + (size_t)(qw + rl) * DD + 32 * hi;
  const i32x8 q80 = mk8(LD16(qrow), LD16(qrow + 16));
  const i32x8 q81 = mk8(LD16(qrow + 64), LD16(qrow + 80));

  f32x16 o[4];
#pragma unroll
  for (int dt = 0; dt < 4; ++dt)
#pragma unroll
    for (int r = 0; r < 16; ++r) o[dt][r] = 0.f;
  float lsum = 0.f;

  stage(pst, 0);

  for (int pp = 0; pp < nph; ++pp) {
    const int buf = pp & 1;
    int pc = pp + pst;
    if (pc >= nph) pc -= nph;

    __builtin_amdgcn_sched_barrier(0);
    asm volatile("s_waitcnt vmcnt(0)" ::: "memory");  // own stage landed
    __builtin_amdgcn_sched_barrier(0);
    __builtin_amdgcn_s_barrier();                     // phase published
    __builtin_amdgcn_sched_barrier(0);
    if (pp + 1 < nph) {
      int pn = pc + 1;
      if (pn >= nph) pn -= nph;
      stage(pn, buf ^ 1);
    }

    const uint8_t* kA = &LDSU[buf][0][0];
    const uint8_t* kB = &LDSU[buf][1][0];
    const uint8_t* vA = &LDSU[buf][2][0];
    const uint8_t* vB = &LDSU[buf][3][0];

    // interleaved 2-tile schedule: SM_A overlaps QK_B; SM_B overlaps PV_A
    f32x16 sA0 = {}, sA1 = {}, sB0 = {}, sB1 = {};
    QKT(kA, sA0, sA1);
    QKT(kB, sB0, sB1);
    uint32_t WA0[4], WA1[4], WB0[4], WB1[4];
    SMPACK(sA0, WA0);
    SMPACK(sA1, WA1);
    MKPA(paA, WA0, WA1);
    PVT(vA, paA);
    SMPACK(sB0, WB0);
    SMPACK(sB1, WB1);
    MKPA(paB, WB0, WB1);
    PVT(vB, paB);
  }

  // L[q]: lanes l and l+32 hold complementary k-subsets of the same q
  const float lt = lsum + __shfl_xor(lsum, 32);
  if (hi == 0) Lp[(size_t)split * NN + qw + rl] = lt;

  float* Ob = Op + (size_t)split * NN * DD;
#pragma unroll
  for (int dt = 0; dt < 4; ++dt)
#pragma unroll
    for (int r = 0; r < 16; ++r) {
      const int q = (r & 3) + 8 * (r >> 2) + 4 * hi;
      Ob[(size_t)(qw + q) * DD + dt * 32 + rl] = o[dt][r];
    }
}

// K3: combine splits, y = 1.5x - 0.5*(O/L), LayerNorm over D, write fp32 out.
__global__ void k_final(const float* __restrict__ x, const float* __restrict__ gamma,
                        const float* __restrict__ beta, const float* __restrict__ Op,
                        const float* __restrict__ Lp, float* __restrict__ out, int nsplit) {
  const int wave = threadIdx.x >> 6, lane = threadIdx.x & 63;
  const int row = blockIdx.x * 4 + wave;
  float o0 = 0.f, o1 = 0.f, lt = 0.f;
  for (int s = 0; s < nsplit; ++s) {
    const float2 v = *reinterpret_cast<const float2*>(
        Op + (size_t)s * NN * DD + (size_t)row * DD + 2 * lane);
    o0 += v.x;
    o1 += v.y;
    lt += Lp[(size_t)s * NN + row];
  }
  const float inv = 1.0f / lt;
  const float2 xv = *reinterpret_cast<const float2*>(x + (size_t)row * DD + 2 * lane);
  float y0 = 1.5f * xv.x - 0.5f * o0 * inv;
  float y1 = 1.5f * xv.y - 0.5f * o1 * inv;
  float sum = y0 + y1;
#pragma unroll
  for (int m = 1; m < 64; m <<= 1) sum += __shfl_xor(sum, m);
  const float mu = sum * (1.0f / 128.0f);
  const float d0 = y0 - mu, d1 = y1 - mu;
  float vs = d0 * d0 + d1 * d1;
#pragma unroll
  for (int m = 1; m < 64; m <<= 1) vs += __shfl_xor(vs, m);
  const float rs = rsqrtf(vs * (1.0f / 128.0f) + 1e-5f);
  const float2 g = *reinterpret_cast<const float2*>(gamma + 2 * lane);
  const float2 b = *reinterpret_cast<const float2*>(beta + 2 * lane);
  float2 ov;
  ov.x = d0 * rs * g.x + b.x;
  ov.y = d1 * rs * g.y + b.y;
  *reinterpret_cast<float2*>(out + (size_t)row * DD + 2 * lane) = ov;
}

extern "C" void kernel_launch(void* const* d_in, const int* in_sizes, int n_in,
                              void* d_out, int out_size, void* d_ws, size_t ws_size,
                              hipStream_t stream) {
  const float* x = (const float*)d_in[0];
  const float* gamma = (const float*)d_in[1];
  const float* beta = (const float*)d_in[2];
  float* out = (float*)d_out;
  char* ws = (char*)d_ws;

  uint8_t* nx = (uint8_t*)ws;                           // 2 MiB fp8 [N][D], scaled
  uint8_t* xT = (uint8_t*)(ws + (size_t)NN * DD);       // 2 MiB fp8 [D][N]
  const size_t base = (size_t)2 * NN * DD;
  const size_t per = (size_t)NN * DD * 4 + (size_t)NN * 4;  // per-split O + L

  int nsplit = 2;
  if (ws_size >= base + 4 * per) nsplit = 4;

  float* Op = (float*)(ws + base);
  float* Lp = (float*)(ws + base + (size_t)nsplit * NN * DD * 4);

  k_norm<<<NN / 4, 256, 0, stream>>>(x, nx);
  k_transpose<<<NN / 64, 256, 0, stream>>>(x, xT);
  if (nsplit == 4)
    k_attn<4><<<dim3(128 * 4), 256, 0, stream>>>(nx, xT, Op, Lp);
  else
    k_attn<2><<<dim3(128 * 2), 256, 0, stream>>>(nx, xT, Op, Lp);
  k_final<<<NN / 4, 256, 0, stream>>>(x, gamma, beta, Op, Lp, out, nsplit);
}